// Round 3
// baseline (277.486 us; speedup 1.0000x reference)
//
#include <hip/hip_runtime.h>
#include <math.h>

#define N 2048
#define BATCH 16

typedef float f32x4 __attribute__((ext_vector_type(4)));  // clang vector: OK for nontemporal builtins

// ---------------------------------------------------------------------------
// Kernel 1: Bsum[b][j] = sum_k |s[b][j] - s[b][k]|
// grid = BATCH*16 = 256 blocks, 128 threads; each block stages the full
// 2048-float score row in LDS (8 KB) and computes 128 j's. ~5 us total.
// ---------------------------------------------------------------------------
__global__ __launch_bounds__(128) void bsum_kernel(const float* __restrict__ scores,
                                                   float* __restrict__ dsum) {
    __shared__ float s_sh[N];
    const int b = blockIdx.x >> 4;
    const int jBase = (blockIdx.x & 15) * 128;
    const float* s = scores + (size_t)b * N;

    for (int t = threadIdx.x; t < N / 4; t += 128) {
        ((float4*)s_sh)[t] = ((const float4*)s)[t];
    }
    __syncthreads();

    const int j = jBase + threadIdx.x;
    const float sj = s_sh[j];
    float acc = 0.f;
#pragma unroll 8
    for (int k = 0; k < N / 4; ++k) {
        float4 v = ((const float4*)s_sh)[k];   // broadcast read: conflict-free
        acc += fabsf(sj - v.x) + fabsf(sj - v.y) + fabsf(sj - v.z) + fabsf(sj - v.w);
    }
    dsum[(size_t)b * N + j] = acc;
}

// ---------------------------------------------------------------------------
// Kernel 2: P_hat[b][i][j] = softmax_j( scaling[i]*s[j] - Bsum[j] )
// One wave per 4 output rows. No LDS, no syncthreads: each wave loads the
// 8 KB s-row + 8 KB Bsum-row ONCE into registers (float4 x8 each, coalesced
// L2 hits) and reuses them across its 4 rows. Nontemporal float4 stores so
// the 256 MB output stream doesn't evict the 256 KB input set from L2.
// grid = 32768 rows / 16 rows-per-block = 2048 blocks of 256 threads.
// ---------------------------------------------------------------------------
__global__ __launch_bounds__(256) void softmax_kernel(const float* __restrict__ scores,
                                                      const float* __restrict__ dsum,
                                                      float* __restrict__ out) {
    const int waveId = blockIdx.x * 4 + (threadIdx.x >> 6);
    const int lane = threadIdx.x & 63;
    const int rowBase = waveId * 4;           // 4 consecutive rows per wave
    const int b = rowBase >> 11;              // rows per batch = 2048
    const int i0 = rowBase & 2047;

    const float4* s4p = (const float4*)(scores + (size_t)b * N);
    const float4* d4p = (const float4*)(dsum + (size_t)b * N);

    float4 s4[8], d4[8];
#pragma unroll
    for (int it = 0; it < 8; ++it) {
        s4[it] = s4p[it * 64 + lane];
        d4[it] = d4p[it * 64 + lane];
    }

#pragma unroll 1
    for (int r = 0; r < 4; ++r) {
        const int row = i0 + r;
        const float c = (float)(N - 1 - 2 * row);   // scaling[i]

        float lg[32];
        float m = -INFINITY;
#pragma unroll
        for (int it = 0; it < 8; ++it) {
            float l0 = fmaf(c, s4[it].x, -d4[it].x);
            float l1 = fmaf(c, s4[it].y, -d4[it].y);
            float l2 = fmaf(c, s4[it].z, -d4[it].z);
            float l3 = fmaf(c, s4[it].w, -d4[it].w);
            lg[it * 4 + 0] = l0;
            lg[it * 4 + 1] = l1;
            lg[it * 4 + 2] = l2;
            lg[it * 4 + 3] = l3;
            m = fmaxf(m, fmaxf(fmaxf(l0, l1), fmaxf(l2, l3)));
        }
#pragma unroll
        for (int off = 32; off > 0; off >>= 1)
            m = fmaxf(m, __shfl_xor(m, off, 64));

        float sum = 0.f;
#pragma unroll
        for (int k = 0; k < 32; ++k) {
            lg[k] = __expf(lg[k] - m);
            sum += lg[k];
        }
#pragma unroll
        for (int off = 32; off > 0; off >>= 1)
            sum += __shfl_xor(sum, off, 64);

        const float inv = 1.0f / sum;

        f32x4* orow = (f32x4*)(out + (((size_t)b * N) + row) * N);
#pragma unroll
        for (int it = 0; it < 8; ++it) {
            f32x4 o;
            o.x = lg[it * 4 + 0] * inv;
            o.y = lg[it * 4 + 1] * inv;
            o.z = lg[it * 4 + 2] * inv;
            o.w = lg[it * 4 + 3] * inv;
            __builtin_nontemporal_store(o, &orow[it * 64 + lane]);
        }
    }
}

extern "C" void kernel_launch(void* const* d_in, const int* in_sizes, int n_in,
                              void* d_out, int out_size, void* d_ws, size_t ws_size,
                              hipStream_t stream) {
    const float* scores = (const float*)d_in[0];
    float* out = (float*)d_out;
    float* dsum = (float*)d_ws;   // BATCH*N floats = 128 KB scratch

    bsum_kernel<<<BATCH * 16, 128, 0, stream>>>(scores, dsum);
    softmax_kernel<<<32768 / 16, 256, 0, stream>>>(scores, dsum, out);
}

// Round 4
// 275.591 us; speedup vs baseline: 1.0069x; 1.0069x over previous
//
#include <hip/hip_runtime.h>
#include <math.h>

#define N 2048
#define BATCH 16

typedef float f32x4 __attribute__((ext_vector_type(4)));

// ---------------------------------------------------------------------------
// Kernel 1: Bsum[b][j] = sum_k |s[b][j] - s[b][k]|
// 256 blocks x 128 threads; each block stages the 2048-float score row in LDS
// (8 KB) and computes 128 j's. ~3 us.
// ---------------------------------------------------------------------------
__global__ __launch_bounds__(128) void bsum_kernel(const float* __restrict__ scores,
                                                   float* __restrict__ dsum) {
    __shared__ float s_sh[N];
    const int b = blockIdx.x >> 4;
    const int jBase = (blockIdx.x & 15) * 128;
    const float* s = scores + (size_t)b * N;

    for (int t = threadIdx.x; t < N / 4; t += 128) {
        ((float4*)s_sh)[t] = ((const float4*)s)[t];
    }
    __syncthreads();

    const int j = jBase + threadIdx.x;
    const float sj = s_sh[j];
    float acc = 0.f;
#pragma unroll 8
    for (int k = 0; k < N / 4; ++k) {
        float4 v = ((const float4*)s_sh)[k];   // broadcast: conflict-free
        acc += fabsf(sj - v.x) + fabsf(sj - v.y) + fabsf(sj - v.z) + fabsf(sj - v.w);
    }
    dsum[(size_t)b * N + j] = acc;
}

// ---------------------------------------------------------------------------
// Kernel 2: per-row stats. q[row] = m_row + ln( sum_j exp(logit_j - m_row) )
// where logit_j = c_row*s_j - Bsum_j.  One wave per 4 rows, registers only.
// 2048 blocks x 256 threads. ~5 us.
// ---------------------------------------------------------------------------
__global__ __launch_bounds__(256) void stats_kernel(const float* __restrict__ scores,
                                                    const float* __restrict__ dsum,
                                                    float* __restrict__ qout) {
    const int waveId = blockIdx.x * 4 + (threadIdx.x >> 6);
    const int lane = threadIdx.x & 63;
    const int rowBase = waveId * 4;           // 4 consecutive rows per wave
    const int b = rowBase >> 11;
    const int i0 = rowBase & 2047;

    const float4* s4p = (const float4*)(scores + (size_t)b * N);
    const float4* d4p = (const float4*)(dsum + (size_t)b * N);

    float4 s4[8], d4[8];
#pragma unroll
    for (int it = 0; it < 8; ++it) {
        s4[it] = s4p[it * 64 + lane];
        d4[it] = d4p[it * 64 + lane];
    }

#pragma unroll 1
    for (int r = 0; r < 4; ++r) {
        const int row = i0 + r;
        const float c = (float)(N - 1 - 2 * row);

        float lg[32];
        float m = -INFINITY;
#pragma unroll
        for (int it = 0; it < 8; ++it) {
            float l0 = fmaf(c, s4[it].x, -d4[it].x);
            float l1 = fmaf(c, s4[it].y, -d4[it].y);
            float l2 = fmaf(c, s4[it].z, -d4[it].z);
            float l3 = fmaf(c, s4[it].w, -d4[it].w);
            lg[it * 4 + 0] = l0; lg[it * 4 + 1] = l1;
            lg[it * 4 + 2] = l2; lg[it * 4 + 3] = l3;
            m = fmaxf(m, fmaxf(fmaxf(l0, l1), fmaxf(l2, l3)));
        }
#pragma unroll
        for (int off = 32; off > 0; off >>= 1)
            m = fmaxf(m, __shfl_xor(m, off, 64));

        float sum = 0.f;
#pragma unroll
        for (int k = 0; k < 32; ++k)
            sum += __expf(lg[k] - m);
#pragma unroll
        for (int off = 32; off > 0; off >>= 1)
            sum += __shfl_xor(sum, off, 64);

        if (lane == 0)
            qout[rowBase + r] = m + __logf(sum);
    }
}

// ---------------------------------------------------------------------------
// Kernel 3: pure streaming writer (fill-shaped).
// out[row][j] = exp( c_row*s_j - Bsum_j - q_row ).
// Each block covers 1024 consecutive j of ONE row -> row constants are
// wave-uniform scalars. Each thread: 2 dwordx4 loads (L2-hit), 4 exps,
// 1 dwordx4 store. 65536 blocks x 256 threads. Target: ~45 us @ ~6 TB/s.
// ---------------------------------------------------------------------------
__global__ __launch_bounds__(256) void write_kernel(const float* __restrict__ scores,
                                                    const float* __restrict__ dsum,
                                                    const float* __restrict__ q,
                                                    float* __restrict__ out) {
    const int blk = blockIdx.x;
    const int row = blk >> 1;                  // global row in [0, 32768)
    const int b = row >> 11;
    const int i = row & 2047;
    const int jBase = (blk & 1) * 1024 + threadIdx.x * 4;

    const float c = (float)(N - 1 - 2 * i);
    const float qv = q[row];

    const float4 s4 = *(const float4*)(scores + (size_t)b * N + jBase);
    const float4 B4 = *(const float4*)(dsum + (size_t)b * N + jBase);

    f32x4 o;
    o.x = __expf(fmaf(c, s4.x, -B4.x) - qv);
    o.y = __expf(fmaf(c, s4.y, -B4.y) - qv);
    o.z = __expf(fmaf(c, s4.z, -B4.z) - qv);
    o.w = __expf(fmaf(c, s4.w, -B4.w) - qv);

    *(f32x4*)(out + (size_t)row * N + jBase) = o;
}

extern "C" void kernel_launch(void* const* d_in, const int* in_sizes, int n_in,
                              void* d_out, int out_size, void* d_ws, size_t ws_size,
                              hipStream_t stream) {
    const float* scores = (const float*)d_in[0];
    float* out = (float*)d_out;
    float* dsum = (float*)d_ws;                    // 32768 floats
    float* q = (float*)d_ws + BATCH * N;           // 32768 floats

    bsum_kernel<<<BATCH * 16, 128, 0, stream>>>(scores, dsum);
    stats_kernel<<<BATCH * N / 16, 256, 0, stream>>>(scores, dsum, q);
    write_kernel<<<BATCH * N * 2, 256, 0, stream>>>(scores, dsum, q, out);
}